// Round 1
// baseline (2041.744 us; speedup 1.0000x reference)
//
#include <hip/hip_runtime.h>
#include <math.h>

// ---------------------------------------------------------------------------
// GINE x3 + global_add_pool + Bayesian head, all fp32.
// Buffers in d_ws: buf0 (h, N*256), buf1 (agg, N*256), buf2 (tmp/hg, N*256),
//                  w1buf (256*256) -> ~154 MB total.
// ---------------------------------------------------------------------------

#define THREADS 256

// ---------------- message + scatter: agg[dst] += relu(h[src] + ea @ We + be)
template<int D, int EPB>
__global__ __launch_bounds__(THREADS) void msg_scatter_kernel(
    const float* __restrict__ h,          // [N, D]
    const float* __restrict__ edge_attr,  // [E, 16]
    const int*   __restrict__ ei,         // [2, E]
    const float* __restrict__ We,         // [16, D]
    const float* __restrict__ be,         // [D]
    float*       __restrict__ agg,        // [N, D]
    int E)
{
    constexpr int EPI = THREADS / D;      // edges per inner iteration (1 or 2)
    __shared__ float ea_s[EPB][16];
    __shared__ int   src_s[EPB];
    __shared__ int   dst_s[EPB];

    const int t  = threadIdx.x;
    const int e0 = blockIdx.x * EPB;

    for (int idx = t; idx < EPB * 16; idx += THREADS) {
        int e = idx >> 4, i = idx & 15;
        ea_s[e][i] = (e0 + e < E) ? edge_attr[(size_t)(e0 + e) * 16 + i] : 0.f;
    }
    if (t < EPB) {
        int e = e0 + t;
        src_s[t] = (e < E) ? ei[e] : 0;
        dst_s[t] = (e < E) ? ei[E + e] : 0;
    }
    __syncthreads();

    const int k   = t % D;
    const int sub = t / D;
    float w[16];
#pragma unroll
    for (int i = 0; i < 16; i++) w[i] = We[i * D + k];
    const float bk = be[k];

    for (int j = sub; j < EPB; j += EPI) {
        if (e0 + j >= E) break;                 // uniform across block
        float ev = bk;
#pragma unroll
        for (int i = 0; i < 16; i++) ev += w[i] * ea_s[j][i];
        float m = h[(size_t)src_s[j] * D + k] + ev;
        m = fmaxf(m, 0.f);
        atomicAdd(&agg[(size_t)dst_s[j] * D + k], m);
    }
}

// ---------------- fused node MLP GEMM:
// out[r][n] = relu( sum_k A[r][k] * W[k][n] + bias[n] ),  n in [0,256)
// MODE 0: A = (1+eps)*h + agg       MODE 1: A = hin
template<int K, int MODE>
__global__ __launch_bounds__(THREADS) void mlp_gemm_kernel(
    const float* __restrict__ hin,   // [nrows, K]
    const float* __restrict__ agg,   // [nrows, K] (MODE 0 only)
    const float* __restrict__ W,     // [K, 256]
    const float* __restrict__ bias,  // [256]
    const float* __restrict__ epsp,  // [1]       (MODE 0 only)
    float*       __restrict__ out,   // [nrows, 256]
    int nrows)
{
    constexpr int BM = 64, KT = 32, BN = 256;
    __shared__ float As[KT][BM + 4];   // +4 pad: 16B-aligned rows, bank spread
    __shared__ float Bs[KT][BN];

    const int t    = threadIdx.x;
    const int row0 = blockIdx.x * BM;
    const int tx = t & 15, ty = t >> 4;
    const int m0 = ty * 4, n0 = tx * 16;

    float scale = 1.0f;
    if (MODE == 0) scale = 1.0f + epsp[0];

    float acc[4][16];
#pragma unroll
    for (int a = 0; a < 4; a++)
#pragma unroll
        for (int b = 0; b < 16; b++) acc[a][b] = 0.f;

    for (int k0 = 0; k0 < K; k0 += KT) {
        // A tile: 64 rows x 32 k (8 elems/thread)
#pragma unroll
        for (int c = 0; c < (BM * KT) / THREADS; c++) {
            int idx = t + c * THREADS;
            int r   = idx >> 5;
            int kk  = idx & 31;
            int row = row0 + r;
            float v = 0.f;
            if (row < nrows) {
                size_t g = (size_t)row * K + k0 + kk;
                v = (MODE == 0) ? (scale * hin[g] + agg[g]) : hin[g];
            }
            As[kk][r] = v;
        }
        // B tile: 32 k x 256 n (32 elems/thread, k==c, n==t)
#pragma unroll
        for (int c = 0; c < KT; c++) {
            Bs[c][t] = W[(size_t)(k0 + c) * 256 + t];
        }
        __syncthreads();

#pragma unroll
        for (int kk = 0; kk < KT; kk++) {
            float a[4], b[16];
#pragma unroll
            for (int mm = 0; mm < 4; mm++) a[mm] = As[kk][m0 + mm];
#pragma unroll
            for (int j = 0; j < 16; j++) b[j] = Bs[kk][n0 + j];
#pragma unroll
            for (int mm = 0; mm < 4; mm++)
#pragma unroll
                for (int j = 0; j < 16; j++) acc[mm][j] += a[mm] * b[j];
        }
        __syncthreads();
    }

#pragma unroll
    for (int mm = 0; mm < 4; mm++) {
        int row = row0 + m0 + mm;
        if (row < nrows) {
#pragma unroll
            for (int j = 0; j < 16; j++) {
                float v = acc[mm][j] + bias[n0 + j];
                out[(size_t)row * 256 + n0 + j] = fmaxf(v, 0.f);
            }
        }
    }
}

// ---------------- global add pool (batch sorted: run-length compress atomics)
__global__ __launch_bounds__(THREADS) void pool_kernel(
    const float* __restrict__ h,      // [N, 256]
    const int*   __restrict__ batch,  // [N]
    float*       __restrict__ hg,     // [G, 256]
    int nnodes)
{
    constexpr int CH = 64;
    __shared__ int b_s[CH];
    const int t  = threadIdx.x;
    const int v0 = blockIdx.x * CH;
    int cnt = nnodes - v0;
    if (cnt > CH) cnt = CH;
    if (cnt <= 0) return;
    if (t < cnt) b_s[t] = batch[v0 + t];
    __syncthreads();

    int curb  = b_s[0];
    float acc = 0.f;
    for (int v = 0; v < cnt; v++) {
        int b = b_s[v];
        if (b != curb) {
            atomicAdd(&hg[(size_t)curb * 256 + t], acc);
            acc = 0.f; curb = b;
        }
        acc += h[(size_t)(v0 + v) * 256 + t];
    }
    atomicAdd(&hg[(size_t)curb * 256 + t], acc);
}

// ---------------- Bayesian weight materialization: w = mu + exp(ls)*eps
__global__ void wprep_kernel(const float* __restrict__ mu,
                             const float* __restrict__ ls,
                             const float* __restrict__ eps,
                             float* __restrict__ w, int n)
{
    int i = blockIdx.x * THREADS + threadIdx.x;
    if (i < n) w[i] = mu[i] + expf(ls[i]) * eps[i];
}

// ---------------- head: out[g] = silu(hg @ w1 + b1) @ w2 + b2
__global__ __launch_bounds__(THREADS) void head_kernel(
    const float* __restrict__ hg,     // [G, 256]
    const float* __restrict__ w1,     // [256, 256] materialized
    const float* __restrict__ h1_bmu, const float* __restrict__ h1_bls,
    const float* __restrict__ eps_b1,
    const float* __restrict__ h2_wmu, const float* __restrict__ h2_wls,
    const float* __restrict__ eps_w2,
    const float* __restrict__ h2_bmu, const float* __restrict__ h2_bls,
    const float* __restrict__ eps_b2,
    float* __restrict__ out)          // [G, 2]
{
    __shared__ float x_s[256];
    __shared__ float red[256];
    const int t = threadIdx.x;
    const int g = blockIdx.x;

    x_s[t] = hg[(size_t)g * 256 + t];
    __syncthreads();

    float acc = h1_bmu[t] + expf(h1_bls[t]) * eps_b1[t];
    for (int kk = 0; kk < 256; kk++) acc += x_s[kk] * w1[kk * 256 + t];
    float h1v = acc / (1.f + expf(-acc));   // silu

    float w2a = h2_wmu[t * 2 + 0] + expf(h2_wls[t * 2 + 0]) * eps_w2[t * 2 + 0];
    float w2b = h2_wmu[t * 2 + 1] + expf(h2_wls[t * 2 + 1]) * eps_w2[t * 2 + 1];

    red[t] = h1v * w2a;
    __syncthreads();
    for (int s = 128; s > 0; s >>= 1) {
        if (t < s) red[t] += red[t + s];
        __syncthreads();
    }
    if (t == 0) out[(size_t)g * 2 + 0] = red[0] + h2_bmu[0] + expf(h2_bls[0]) * eps_b2[0];
    __syncthreads();

    red[t] = h1v * w2b;
    __syncthreads();
    for (int s = 128; s > 0; s >>= 1) {
        if (t < s) red[t] += red[t + s];
        __syncthreads();
    }
    if (t == 0) out[(size_t)g * 2 + 1] = red[0] + h2_bmu[1] + expf(h2_bls[1]) * eps_b2[1];
}

// ---------------------------------------------------------------------------
extern "C" void kernel_launch(void* const* d_in, const int* in_sizes, int n_in,
                              void* d_out, int out_size, void* d_ws, size_t ws_size,
                              hipStream_t stream)
{
    const float* x         = (const float*)d_in[0];
    const float* edge_attr = (const float*)d_in[1];
    const int*   ei        = (const int*)d_in[2];
    const int*   batch     = (const int*)d_in[3];

    const float* We[3]  = { (const float*)d_in[4],  (const float*)d_in[11], (const float*)d_in[18] };
    const float* be[3]  = { (const float*)d_in[5],  (const float*)d_in[12], (const float*)d_in[19] };
    const float* W1[3]  = { (const float*)d_in[6],  (const float*)d_in[13], (const float*)d_in[20] };
    const float* b1[3]  = { (const float*)d_in[7],  (const float*)d_in[14], (const float*)d_in[21] };
    const float* W2[3]  = { (const float*)d_in[8],  (const float*)d_in[15], (const float*)d_in[22] };
    const float* b2[3]  = { (const float*)d_in[9],  (const float*)d_in[16], (const float*)d_in[23] };
    const float* epsl[3]= { (const float*)d_in[10], (const float*)d_in[17], (const float*)d_in[24] };

    const float* h1_wmu = (const float*)d_in[25];
    const float* h1_wls = (const float*)d_in[26];
    const float* h1_bmu = (const float*)d_in[27];
    const float* h1_bls = (const float*)d_in[28];
    const float* h2_wmu = (const float*)d_in[29];
    const float* h2_wls = (const float*)d_in[30];
    const float* h2_bmu = (const float*)d_in[31];
    const float* h2_bls = (const float*)d_in[32];
    const float* eps_w1 = (const float*)d_in[33];
    const float* eps_b1 = (const float*)d_in[34];
    const float* eps_w2 = (const float*)d_in[35];
    const float* eps_b2 = (const float*)d_in[36];

    const int N = in_sizes[0] / 128;
    const int E = in_sizes[1] / 16;
    const int G = out_size / 2;

    float* buf0  = (float*)d_ws;                 // h
    float* buf1  = buf0 + (size_t)N * 256;       // agg
    float* buf2  = buf1 + (size_t)N * 256;       // tmp / hg
    float* w1buf = buf2 + (size_t)N * 256;       // 256*256

    constexpr int EPB = 32;
    const int msg_blocks  = (E + EPB - 1) / EPB;
    const int gemm_blocks = (N + 63) / 64;
    const int pool_blocks = (N + 63) / 64;

    float* out = (float*)d_out;

    // ---- layer 0 (d = 128, h = x)
    hipMemsetAsync(buf1, 0, (size_t)N * 128 * sizeof(float), stream);
    msg_scatter_kernel<128, EPB><<<msg_blocks, THREADS, 0, stream>>>(
        x, edge_attr, ei, We[0], be[0], buf1, E);
    mlp_gemm_kernel<128, 0><<<gemm_blocks, THREADS, 0, stream>>>(
        x, buf1, W1[0], b1[0], epsl[0], buf2, N);
    mlp_gemm_kernel<256, 1><<<gemm_blocks, THREADS, 0, stream>>>(
        buf2, nullptr, W2[0], b2[0], nullptr, buf0, N);

    // ---- layers 1, 2 (d = 256)
    for (int l = 1; l < 3; l++) {
        hipMemsetAsync(buf1, 0, (size_t)N * 256 * sizeof(float), stream);
        msg_scatter_kernel<256, EPB><<<msg_blocks, THREADS, 0, stream>>>(
            buf0, edge_attr, ei, We[l], be[l], buf1, E);
        mlp_gemm_kernel<256, 0><<<gemm_blocks, THREADS, 0, stream>>>(
            buf0, buf1, W1[l], b1[l], epsl[l], buf2, N);
        mlp_gemm_kernel<256, 1><<<gemm_blocks, THREADS, 0, stream>>>(
            buf2, nullptr, W2[l], b2[l], nullptr, buf0, N);
    }

    // ---- global add pool -> buf2[0 .. G*256)
    hipMemsetAsync(buf2, 0, (size_t)G * 256 * sizeof(float), stream);
    pool_kernel<<<pool_blocks, THREADS, 0, stream>>>(buf0, batch, buf2, N);

    // ---- Bayesian head
    wprep_kernel<<<(256 * 256 + THREADS - 1) / THREADS, THREADS, 0, stream>>>(
        h1_wmu, h1_wls, eps_w1, w1buf, 256 * 256);
    head_kernel<<<G, THREADS, 0, stream>>>(
        buf2, w1buf, h1_bmu, h1_bls, eps_b1,
        h2_wmu, h2_wls, eps_w2, h2_bmu, h2_bls, eps_b2, out);
}

// Round 2
// 1597.431 us; speedup vs baseline: 1.2781x; 1.2781x over previous
//
#include <hip/hip_runtime.h>
#include <math.h>

// ---------------------------------------------------------------------------
// GINE x3 + global_add_pool + Bayesian head, all fp32.
// Round 2: replace atomic scatter with CSR (dst-sorted) gather-aggregate.
// CSR built once per call (edge_index identical across layers).
// ---------------------------------------------------------------------------

#define THREADS 256

// ---------------- CSR build: histogram of dst
__global__ __launch_bounds__(THREADS) void hist_kernel(
    const int* __restrict__ ei, int* __restrict__ deg, int E)
{
    int e = blockIdx.x * THREADS + threadIdx.x;
    if (e < E) atomicAdd(&deg[ei[E + e]], 1);
}

// ---------------- CSR build: single-block exclusive scan -> rowptr[0..n]
__global__ __launch_bounds__(1024) void scan_kernel(
    const int* __restrict__ deg, int* __restrict__ rowptr, int n)
{
    __shared__ int s[1024];
    __shared__ int carry_s;
    const int t = threadIdx.x;
    if (t == 0) carry_s = 0;
    __syncthreads();
    for (int base = 0; base < n; base += 1024) {
        int i = base + t;
        s[t] = (i < n) ? deg[i] : 0;
        __syncthreads();
        for (int off = 1; off < 1024; off <<= 1) {
            int add = (t >= off) ? s[t - off] : 0;
            __syncthreads();
            s[t] += add;
            __syncthreads();
        }
        int incl = s[t];
        int carry = carry_s;                 // stable since previous chunk
        if (i < n) rowptr[i + 1] = carry + incl;
        __syncthreads();
        if (t == 1023) carry_s = carry + incl;
        __syncthreads();
    }
    if (t == 0) rowptr[0] = 0;
}

// ---------------- CSR build: scatter edge ids into slots
__global__ __launch_bounds__(THREADS) void fill_kernel(
    const int* __restrict__ ei, const int* __restrict__ rowptr,
    int* __restrict__ cursor, int* __restrict__ csr_src,
    int* __restrict__ csr_eid, int E)
{
    int e = blockIdx.x * THREADS + threadIdx.x;
    if (e >= E) return;
    int s = ei[e], d = ei[E + e];
    int pos  = atomicAdd(&cursor[d], 1);
    int slot = rowptr[d] + pos;
    csr_src[slot] = s;
    csr_eid[slot] = e;
}

// ---------------- aggregation: agg[n][k] = sum_{e: dst=n} relu(h[src][k]+proj)
template<int D>
__global__ __launch_bounds__(THREADS) void csr_agg_kernel(
    const float* __restrict__ h,          // [N, D]
    const float* __restrict__ edge_attr,  // [E, 16]
    const int*   __restrict__ rowptr,
    const int*   __restrict__ csr_src,
    const int*   __restrict__ csr_eid,
    const float* __restrict__ We,         // [16, D]
    const float* __restrict__ be,         // [D]
    float*       __restrict__ agg,        // [N, D]
    int nnodes)
{
    constexpr int NPB = THREADS / D;
    const int t   = threadIdx.x;
    const int k   = (NPB == 1) ? t : (t & (D - 1));
    const int sub = (NPB == 1) ? 0 : (t / D);
    const int n   = blockIdx.x * NPB + sub;
    if (n >= nnodes) return;

    float w[16];
#pragma unroll
    for (int i = 0; i < 16; i++) w[i] = We[i * D + k];
    const float bk = be[k];

    float acc = 0.f;
    const int beg = rowptr[n], end = rowptr[n + 1];
    for (int s = beg; s < end; ++s) {
        int src = csr_src[s];
        int eid = csr_eid[s];
        const float4* ea = (const float4*)(edge_attr + (size_t)eid * 16);
        float4 a0 = ea[0], a1 = ea[1], a2 = ea[2], a3 = ea[3];
        float ev = bk;
        ev += w[0]  * a0.x + w[1]  * a0.y + w[2]  * a0.z + w[3]  * a0.w;
        ev += w[4]  * a1.x + w[5]  * a1.y + w[6]  * a1.z + w[7]  * a1.w;
        ev += w[8]  * a2.x + w[9]  * a2.y + w[10] * a2.z + w[11] * a2.w;
        ev += w[12] * a3.x + w[13] * a3.y + w[14] * a3.z + w[15] * a3.w;
        float m = h[(size_t)src * D + k] + ev;
        acc += fmaxf(m, 0.f);
    }
    agg[(size_t)n * D + k] = acc;
}

// ---------------- fused node MLP GEMM:
// out[r][n] = relu( sum_k A[r][k] * W[k][n] + bias[n] ),  n in [0,256)
// MODE 0: A = (1+eps)*h + agg       MODE 1: A = hin
template<int K, int MODE>
__global__ __launch_bounds__(THREADS) void mlp_gemm_kernel(
    const float* __restrict__ hin,   // [nrows, K]
    const float* __restrict__ agg,   // [nrows, K] (MODE 0 only)
    const float* __restrict__ W,     // [K, 256]
    const float* __restrict__ bias,  // [256]
    const float* __restrict__ epsp,  // [1]       (MODE 0 only)
    float*       __restrict__ out,   // [nrows, 256]
    int nrows)
{
    constexpr int BM = 64, KT = 32, BN = 256;
    __shared__ float As[KT][BM + 4];
    __shared__ float Bs[KT][BN];

    const int t    = threadIdx.x;
    const int row0 = blockIdx.x * BM;
    const int tx = t & 15, ty = t >> 4;
    const int m0 = ty * 4, n0 = tx * 16;

    float scale = 1.0f;
    if (MODE == 0) scale = 1.0f + epsp[0];

    float acc[4][16];
#pragma unroll
    for (int a = 0; a < 4; a++)
#pragma unroll
        for (int b = 0; b < 16; b++) acc[a][b] = 0.f;

    for (int k0 = 0; k0 < K; k0 += KT) {
#pragma unroll
        for (int c = 0; c < (BM * KT) / THREADS; c++) {
            int idx = t + c * THREADS;
            int r   = idx >> 5;
            int kk  = idx & 31;
            int row = row0 + r;
            float v = 0.f;
            if (row < nrows) {
                size_t g = (size_t)row * K + k0 + kk;
                v = (MODE == 0) ? (scale * hin[g] + agg[g]) : hin[g];
            }
            As[kk][r] = v;
        }
#pragma unroll
        for (int c = 0; c < KT; c++) {
            Bs[c][t] = W[(size_t)(k0 + c) * 256 + t];
        }
        __syncthreads();

#pragma unroll
        for (int kk = 0; kk < KT; kk++) {
            float a[4], b[16];
#pragma unroll
            for (int mm = 0; mm < 4; mm++) a[mm] = As[kk][m0 + mm];
#pragma unroll
            for (int j = 0; j < 16; j++) b[j] = Bs[kk][n0 + j];
#pragma unroll
            for (int mm = 0; mm < 4; mm++)
#pragma unroll
                for (int j = 0; j < 16; j++) acc[mm][j] += a[mm] * b[j];
        }
        __syncthreads();
    }

#pragma unroll
    for (int mm = 0; mm < 4; mm++) {
        int row = row0 + m0 + mm;
        if (row < nrows) {
#pragma unroll
            for (int j = 0; j < 16; j++) {
                float v = acc[mm][j] + bias[n0 + j];
                out[(size_t)row * 256 + n0 + j] = fmaxf(v, 0.f);
            }
        }
    }
}

// ---------------- global add pool (batch sorted: run-length compress atomics)
__global__ __launch_bounds__(THREADS) void pool_kernel(
    const float* __restrict__ h,      // [N, 256]
    const int*   __restrict__ batch,  // [N]
    float*       __restrict__ hg,     // [G, 256]
    int nnodes)
{
    constexpr int CH = 64;
    __shared__ int b_s[CH];
    const int t  = threadIdx.x;
    const int v0 = blockIdx.x * CH;
    int cnt = nnodes - v0;
    if (cnt > CH) cnt = CH;
    if (cnt <= 0) return;
    if (t < cnt) b_s[t] = batch[v0 + t];
    __syncthreads();

    int curb  = b_s[0];
    float acc = 0.f;
    for (int v = 0; v < cnt; v++) {
        int b = b_s[v];
        if (b != curb) {
            atomicAdd(&hg[(size_t)curb * 256 + t], acc);
            acc = 0.f; curb = b;
        }
        acc += h[(size_t)(v0 + v) * 256 + t];
    }
    atomicAdd(&hg[(size_t)curb * 256 + t], acc);
}

// ---------------- Bayesian weight materialization: w = mu + exp(ls)*eps
__global__ void wprep_kernel(const float* __restrict__ mu,
                             const float* __restrict__ ls,
                             const float* __restrict__ eps,
                             float* __restrict__ w, int n)
{
    int i = blockIdx.x * THREADS + threadIdx.x;
    if (i < n) w[i] = mu[i] + expf(ls[i]) * eps[i];
}

// ---------------- head: out[g] = silu(hg @ w1 + b1) @ w2 + b2
__global__ __launch_bounds__(THREADS) void head_kernel(
    const float* __restrict__ hg,     // [G, 256]
    const float* __restrict__ w1,     // [256, 256] materialized
    const float* __restrict__ h1_bmu, const float* __restrict__ h1_bls,
    const float* __restrict__ eps_b1,
    const float* __restrict__ h2_wmu, const float* __restrict__ h2_wls,
    const float* __restrict__ eps_w2,
    const float* __restrict__ h2_bmu, const float* __restrict__ h2_bls,
    const float* __restrict__ eps_b2,
    float* __restrict__ out)          // [G, 2]
{
    __shared__ float x_s[256];
    __shared__ float red[256];
    const int t = threadIdx.x;
    const int g = blockIdx.x;

    x_s[t] = hg[(size_t)g * 256 + t];
    __syncthreads();

    float acc = h1_bmu[t] + expf(h1_bls[t]) * eps_b1[t];
    for (int kk = 0; kk < 256; kk++) acc += x_s[kk] * w1[kk * 256 + t];
    float h1v = acc / (1.f + expf(-acc));   // silu

    float w2a = h2_wmu[t * 2 + 0] + expf(h2_wls[t * 2 + 0]) * eps_w2[t * 2 + 0];
    float w2b = h2_wmu[t * 2 + 1] + expf(h2_wls[t * 2 + 1]) * eps_w2[t * 2 + 1];

    red[t] = h1v * w2a;
    __syncthreads();
    for (int s = 128; s > 0; s >>= 1) {
        if (t < s) red[t] += red[t + s];
        __syncthreads();
    }
    if (t == 0) out[(size_t)g * 2 + 0] = red[0] + h2_bmu[0] + expf(h2_bls[0]) * eps_b2[0];
    __syncthreads();

    red[t] = h1v * w2b;
    __syncthreads();
    for (int s = 128; s > 0; s >>= 1) {
        if (t < s) red[t] += red[t + s];
        __syncthreads();
    }
    if (t == 0) out[(size_t)g * 2 + 1] = red[0] + h2_bmu[1] + expf(h2_bls[1]) * eps_b2[1];
}

// ---------------------------------------------------------------------------
extern "C" void kernel_launch(void* const* d_in, const int* in_sizes, int n_in,
                              void* d_out, int out_size, void* d_ws, size_t ws_size,
                              hipStream_t stream)
{
    const float* x         = (const float*)d_in[0];
    const float* edge_attr = (const float*)d_in[1];
    const int*   ei        = (const int*)d_in[2];
    const int*   batch     = (const int*)d_in[3];

    const float* We[3]  = { (const float*)d_in[4],  (const float*)d_in[11], (const float*)d_in[18] };
    const float* be[3]  = { (const float*)d_in[5],  (const float*)d_in[12], (const float*)d_in[19] };
    const float* W1[3]  = { (const float*)d_in[6],  (const float*)d_in[13], (const float*)d_in[20] };
    const float* b1[3]  = { (const float*)d_in[7],  (const float*)d_in[14], (const float*)d_in[21] };
    const float* W2[3]  = { (const float*)d_in[8],  (const float*)d_in[15], (const float*)d_in[22] };
    const float* b2[3]  = { (const float*)d_in[9],  (const float*)d_in[16], (const float*)d_in[23] };
    const float* epsl[3]= { (const float*)d_in[10], (const float*)d_in[17], (const float*)d_in[24] };

    const float* h1_wmu = (const float*)d_in[25];
    const float* h1_wls = (const float*)d_in[26];
    const float* h1_bmu = (const float*)d_in[27];
    const float* h1_bls = (const float*)d_in[28];
    const float* h2_wmu = (const float*)d_in[29];
    const float* h2_wls = (const float*)d_in[30];
    const float* h2_bmu = (const float*)d_in[31];
    const float* h2_bls = (const float*)d_in[32];
    const float* eps_w1 = (const float*)d_in[33];
    const float* eps_b1 = (const float*)d_in[34];
    const float* eps_w2 = (const float*)d_in[35];
    const float* eps_b2 = (const float*)d_in[36];

    const int N = in_sizes[0] / 128;
    const int E = in_sizes[1] / 16;
    const int G = out_size / 2;

    float* buf0  = (float*)d_ws;                 // h
    float* buf1  = buf0 + (size_t)N * 256;       // agg
    float* buf2  = buf1 + (size_t)N * 256;       // tmp / hg
    float* w1buf = buf2 + (size_t)N * 256;       // 256*256
    int* rowptr  = (int*)(w1buf + 256 * 256);    // N+1
    int* cursor  = rowptr + (N + 1);             // N (deg, then fill cursor)
    int* csr_src = cursor + N;                   // E
    int* csr_eid = csr_src + E;                  // E

    const int eblocks     = (E + THREADS - 1) / THREADS;
    const int gemm_blocks = (N + 63) / 64;
    const int pool_blocks = (N + 63) / 64;

    float* out = (float*)d_out;

    // ---- build CSR once (edge_index identical for all layers)
    hipMemsetAsync(cursor, 0, (size_t)N * sizeof(int), stream);
    hist_kernel<<<eblocks, THREADS, 0, stream>>>(ei, cursor, E);
    scan_kernel<<<1, 1024, 0, stream>>>(cursor, rowptr, N);
    hipMemsetAsync(cursor, 0, (size_t)N * sizeof(int), stream);
    fill_kernel<<<eblocks, THREADS, 0, stream>>>(ei, rowptr, cursor, csr_src, csr_eid, E);

    // ---- layer 0 (d = 128, h = x)
    csr_agg_kernel<128><<<(N + 1) / 2, THREADS, 0, stream>>>(
        x, edge_attr, rowptr, csr_src, csr_eid, We[0], be[0], buf1, N);
    mlp_gemm_kernel<128, 0><<<gemm_blocks, THREADS, 0, stream>>>(
        x, buf1, W1[0], b1[0], epsl[0], buf2, N);
    mlp_gemm_kernel<256, 1><<<gemm_blocks, THREADS, 0, stream>>>(
        buf2, nullptr, W2[0], b2[0], nullptr, buf0, N);

    // ---- layers 1, 2 (d = 256)
    for (int l = 1; l < 3; l++) {
        csr_agg_kernel<256><<<N, THREADS, 0, stream>>>(
            buf0, edge_attr, rowptr, csr_src, csr_eid, We[l], be[l], buf1, N);
        mlp_gemm_kernel<256, 0><<<gemm_blocks, THREADS, 0, stream>>>(
            buf0, buf1, W1[l], b1[l], epsl[l], buf2, N);
        mlp_gemm_kernel<256, 1><<<gemm_blocks, THREADS, 0, stream>>>(
            buf2, nullptr, W2[l], b2[l], nullptr, buf0, N);
    }

    // ---- global add pool -> buf2[0 .. G*256)
    hipMemsetAsync(buf2, 0, (size_t)G * 256 * sizeof(float), stream);
    pool_kernel<<<pool_blocks, THREADS, 0, stream>>>(buf0, batch, buf2, N);

    // ---- Bayesian head
    wprep_kernel<<<(256 * 256 + THREADS - 1) / THREADS, THREADS, 0, stream>>>(
        h1_wmu, h1_wls, eps_w1, w1buf, 256 * 256);
    head_kernel<<<G, THREADS, 0, stream>>>(
        buf2, w1buf, h1_bmu, h1_bls, eps_b1,
        h2_wmu, h2_wls, eps_w2, h2_bmu, h2_bls, eps_b2, out);
}

// Round 3
// 966.595 us; speedup vs baseline: 2.1123x; 1.6526x over previous
//
#include <hip/hip_runtime.h>
#include <hip/hip_bf16.h>
#include <math.h>

// ---------------------------------------------------------------------------
// GINE x3 + global_add_pool + Bayesian head.
// Round 3: node-MLP GEMMs on bf16 MFMA (16x16x32), CSR gather aggregation f32.
// ---------------------------------------------------------------------------

#define THREADS 256

typedef __attribute__((ext_vector_type(8))) short bf16x8;
typedef __attribute__((ext_vector_type(4))) float f32x4;

__device__ __forceinline__ unsigned short f2bf(float x) {
    __hip_bfloat16 h = __float2bfloat16(x);
    return __builtin_bit_cast(unsigned short, h);
}

// ---------------- CSR build: histogram of dst
__global__ __launch_bounds__(THREADS) void hist_kernel(
    const int* __restrict__ ei, int* __restrict__ deg, int E)
{
    int e = blockIdx.x * THREADS + threadIdx.x;
    if (e < E) atomicAdd(&deg[ei[E + e]], 1);
}

// ---------------- CSR build: single-block exclusive scan -> rowptr[0..n]
__global__ __launch_bounds__(1024) void scan_kernel(
    const int* __restrict__ deg, int* __restrict__ rowptr, int n)
{
    __shared__ int s[1024];
    __shared__ int carry_s;
    const int t = threadIdx.x;
    if (t == 0) carry_s = 0;
    __syncthreads();
    for (int base = 0; base < n; base += 1024) {
        int i = base + t;
        s[t] = (i < n) ? deg[i] : 0;
        __syncthreads();
        for (int off = 1; off < 1024; off <<= 1) {
            int add = (t >= off) ? s[t - off] : 0;
            __syncthreads();
            s[t] += add;
            __syncthreads();
        }
        int incl = s[t];
        int carry = carry_s;
        if (i < n) rowptr[i + 1] = carry + incl;
        __syncthreads();
        if (t == 1023) carry_s = carry + incl;
        __syncthreads();
    }
    if (t == 0) rowptr[0] = 0;
}

// ---------------- CSR build: scatter edge ids into slots
__global__ __launch_bounds__(THREADS) void fill_kernel(
    const int* __restrict__ ei, const int* __restrict__ rowptr,
    int* __restrict__ cursor, int* __restrict__ csr_src,
    int* __restrict__ csr_eid, int E)
{
    int e = blockIdx.x * THREADS + threadIdx.x;
    if (e >= E) return;
    int s = ei[e], d = ei[E + e];
    int pos  = atomicAdd(&cursor[d], 1);
    int slot = rowptr[d] + pos;
    csr_src[slot] = s;
    csr_eid[slot] = e;
}

// ---------------- aggregation: agg[n][k] = sum_{e: dst=n} relu(h[src][k]+proj)
template<int D>
__global__ __launch_bounds__(THREADS) void csr_agg_kernel(
    const float* __restrict__ h,          // [N, D]
    const float* __restrict__ edge_attr,  // [E, 16]
    const int*   __restrict__ rowptr,
    const int*   __restrict__ csr_src,
    const int*   __restrict__ csr_eid,
    const float* __restrict__ We,         // [16, D]
    const float* __restrict__ be,         // [D]
    float*       __restrict__ agg,        // [N, D]
    int nnodes)
{
    constexpr int NPB = THREADS / D;
    const int t   = threadIdx.x;
    const int k   = (NPB == 1) ? t : (t & (D - 1));
    const int sub = (NPB == 1) ? 0 : (t / D);
    const int n   = blockIdx.x * NPB + sub;
    if (n >= nnodes) return;

    float w[16];
#pragma unroll
    for (int i = 0; i < 16; i++) w[i] = We[i * D + k];
    const float bk = be[k];

    float acc = 0.f;
    const int beg = rowptr[n], end = rowptr[n + 1];
    for (int s = beg; s < end; ++s) {
        int src = csr_src[s];
        int eid = csr_eid[s];
        const float4* ea = (const float4*)(edge_attr + (size_t)eid * 16);
        float4 a0 = ea[0], a1 = ea[1], a2 = ea[2], a3 = ea[3];
        float ev = bk;
        ev += w[0]  * a0.x + w[1]  * a0.y + w[2]  * a0.z + w[3]  * a0.w;
        ev += w[4]  * a1.x + w[5]  * a1.y + w[6]  * a1.z + w[7]  * a1.w;
        ev += w[8]  * a2.x + w[9]  * a2.y + w[10] * a2.z + w[11] * a2.w;
        ev += w[12] * a3.x + w[13] * a3.y + w[14] * a3.z + w[15] * a3.w;
        float m = h[(size_t)src * D + k] + ev;
        acc += fmaxf(m, 0.f);
    }
    agg[(size_t)n * D + k] = acc;
}

// ---------------- W transpose + bf16 convert: W[K,256] f32 -> Wt[256,K] bf16
__global__ __launch_bounds__(THREADS) void wtrans_kernel(
    const float* __restrict__ W, unsigned short* __restrict__ Wt, int K)
{
    __shared__ float tile[32][33];
    const int kb = blockIdx.x * 32, nb = blockIdx.y * 32;
    const int tx = threadIdx.x & 31, ty = threadIdx.x >> 5;  // ty: 0..7
#pragma unroll
    for (int i = ty; i < 32; i += 8)
        tile[i][tx] = W[(size_t)(kb + i) * 256 + nb + tx];
    __syncthreads();
#pragma unroll
    for (int i = ty; i < 32; i += 8)
        Wt[(size_t)(nb + i) * K + kb + tx] = f2bf(tile[tx][i]);
}

// ---------------- MFMA node-MLP GEMM:
// out[r][n] = relu( A[r][:] @ Wt[n][:] + bias[n] )
// MODE 0: A = (1+eps)*hin + agg    MODE 1: A = hin
template<int K, int MODE>
__global__ __launch_bounds__(THREADS) void mfma_mlp_kernel(
    const float* __restrict__ hin,            // [nrows, K] f32
    const float* __restrict__ agg,            // [nrows, K] f32 (MODE 0)
    const unsigned short* __restrict__ Wt,    // [256, K] bf16
    const float* __restrict__ bias,           // [256]
    const float* __restrict__ epsp,           // [1] (MODE 0)
    float*       __restrict__ out,            // [nrows, 256]
    int nrows)
{
    constexpr int BM = 128, BK = 64;
    constexpr int LDR = BK + 8;               // 72 shorts = 144 B row stride
    __shared__ short As[BM * LDR];
    __shared__ short Bs[128 * LDR];

    const int t    = threadIdx.x;
    const int lane = t & 63;
    const int wid  = t >> 6;
    const int wm   = wid >> 1, wn = wid & 1;
    const int l15  = lane & 15, lgr = lane >> 4;

    const int r0 = blockIdx.x * BM;
    const int n0 = blockIdx.y * 128;

    float scale = 1.0f;
    if (MODE == 0) scale = 1.0f + epsp[0];

    f32x4 acc[4][4];
#pragma unroll
    for (int a = 0; a < 4; a++)
#pragma unroll
        for (int b = 0; b < 4; b++) acc[a][b] = (f32x4){0.f, 0.f, 0.f, 0.f};

    for (int k0 = 0; k0 < K; k0 += BK) {
        // ---- stage A: 128 rows x 64 k, f32 -> bf16 (8 float4 per thread)
#pragma unroll
        for (int c = 0; c < 8; c++) {
            int idx = t + c * THREADS;        // 0..2047
            int r   = idx >> 4;               // 0..127
            int kq  = idx & 15;               // float4 within row
            int row = r0 + r;
            float4 v = make_float4(0.f, 0.f, 0.f, 0.f);
            if (row < nrows) {
                size_t g = (size_t)row * K + k0 + kq * 4;
                v = *(const float4*)(hin + g);
                if (MODE == 0) {
                    float4 a = *(const float4*)(agg + g);
                    v.x = scale * v.x + a.x; v.y = scale * v.y + a.y;
                    v.z = scale * v.z + a.z; v.w = scale * v.w + a.w;
                }
            }
            uint2 p;
            p.x = (unsigned)f2bf(v.x) | ((unsigned)f2bf(v.y) << 16);
            p.y = (unsigned)f2bf(v.z) | ((unsigned)f2bf(v.w) << 16);
            *(uint2*)(&As[r * LDR + kq * 4]) = p;
        }
        // ---- stage B: 128 n-rows x 64 k bf16 (4 x 16B per thread)
#pragma unroll
        for (int c = 0; c < 4; c++) {
            int idx = t + c * THREADS;        // 0..1023
            int n   = idx >> 3;               // 0..127
            int kq  = idx & 7;                // 16B chunk
            uint4 w = *(const uint4*)(Wt + (size_t)(n0 + n) * K + k0 + kq * 8);
            *(uint4*)(&Bs[n * LDR + kq * 8]) = w;
        }
        __syncthreads();

        // ---- compute: 2 k-slices of 32, 4x4 fragments per wave
#pragma unroll
        for (int ks = 0; ks < 2; ks++) {
            bf16x8 af[4], bfr[4];
#pragma unroll
            for (int mf = 0; mf < 4; mf++)
                af[mf] = *(const bf16x8*)(&As[(wm * 64 + mf * 16 + l15) * LDR + ks * 32 + lgr * 8]);
#pragma unroll
            for (int nf = 0; nf < 4; nf++)
                bfr[nf] = *(const bf16x8*)(&Bs[(wn * 64 + nf * 16 + l15) * LDR + ks * 32 + lgr * 8]);
#pragma unroll
            for (int mf = 0; mf < 4; mf++)
#pragma unroll
                for (int nf = 0; nf < 4; nf++)
                    acc[mf][nf] = __builtin_amdgcn_mfma_f32_16x16x32_bf16(
                        af[mf], bfr[nf], acc[mf][nf], 0, 0, 0);
        }
        __syncthreads();
    }

    // ---- epilogue: bias + relu, f32 store
#pragma unroll
    for (int nf = 0; nf < 4; nf++) {
        int col = n0 + wn * 64 + nf * 16 + l15;
        float bcol = bias[col];
#pragma unroll
        for (int mf = 0; mf < 4; mf++) {
            f32x4 v = acc[mf][nf];
#pragma unroll
            for (int r = 0; r < 4; r++) {
                int row = r0 + wm * 64 + mf * 16 + lgr * 4 + r;
                if (row < nrows)
                    out[(size_t)row * 256 + col] = fmaxf(v[r] + bcol, 0.f);
            }
        }
    }
}

// ---------------- global add pool (batch sorted: run-length compress atomics)
__global__ __launch_bounds__(THREADS) void pool_kernel(
    const float* __restrict__ h,      // [N, 256]
    const int*   __restrict__ batch,  // [N]
    float*       __restrict__ hg,     // [G, 256]
    int nnodes)
{
    constexpr int CH = 64;
    __shared__ int b_s[CH];
    const int t  = threadIdx.x;
    const int v0 = blockIdx.x * CH;
    int cnt = nnodes - v0;
    if (cnt > CH) cnt = CH;
    if (cnt <= 0) return;
    if (t < cnt) b_s[t] = batch[v0 + t];
    __syncthreads();

    int curb  = b_s[0];
    float acc = 0.f;
    for (int v = 0; v < cnt; v++) {
        int b = b_s[v];
        if (b != curb) {
            atomicAdd(&hg[(size_t)curb * 256 + t], acc);
            acc = 0.f; curb = b;
        }
        acc += h[(size_t)(v0 + v) * 256 + t];
    }
    atomicAdd(&hg[(size_t)curb * 256 + t], acc);
}

// ---------------- Bayesian weight materialization: w = mu + exp(ls)*eps
__global__ void wprep_kernel(const float* __restrict__ mu,
                             const float* __restrict__ ls,
                             const float* __restrict__ eps,
                             float* __restrict__ w, int n)
{
    int i = blockIdx.x * THREADS + threadIdx.x;
    if (i < n) w[i] = mu[i] + expf(ls[i]) * eps[i];
}

// ---------------- head: out[g] = silu(hg @ w1 + b1) @ w2 + b2
__global__ __launch_bounds__(THREADS) void head_kernel(
    const float* __restrict__ hg,     // [G, 256]
    const float* __restrict__ w1,     // [256, 256] materialized
    const float* __restrict__ h1_bmu, const float* __restrict__ h1_bls,
    const float* __restrict__ eps_b1,
    const float* __restrict__ h2_wmu, const float* __restrict__ h2_wls,
    const float* __restrict__ eps_w2,
    const float* __restrict__ h2_bmu, const float* __restrict__ h2_bls,
    const float* __restrict__ eps_b2,
    float* __restrict__ out)          // [G, 2]
{
    __shared__ float x_s[256];
    __shared__ float red[256];
    const int t = threadIdx.x;
    const int g = blockIdx.x;

    x_s[t] = hg[(size_t)g * 256 + t];
    __syncthreads();

    float acc = h1_bmu[t] + expf(h1_bls[t]) * eps_b1[t];
    for (int kk = 0; kk < 256; kk++) acc += x_s[kk] * w1[kk * 256 + t];
    float h1v = acc / (1.f + expf(-acc));   // silu

    float w2a = h2_wmu[t * 2 + 0] + expf(h2_wls[t * 2 + 0]) * eps_w2[t * 2 + 0];
    float w2b = h2_wmu[t * 2 + 1] + expf(h2_wls[t * 2 + 1]) * eps_w2[t * 2 + 1];

    red[t] = h1v * w2a;
    __syncthreads();
    for (int s = 128; s > 0; s >>= 1) {
        if (t < s) red[t] += red[t + s];
        __syncthreads();
    }
    if (t == 0) out[(size_t)g * 2 + 0] = red[0] + h2_bmu[0] + expf(h2_bls[0]) * eps_b2[0];
    __syncthreads();

    red[t] = h1v * w2b;
    __syncthreads();
    for (int s = 128; s > 0; s >>= 1) {
        if (t < s) red[t] += red[t + s];
        __syncthreads();
    }
    if (t == 0) out[(size_t)g * 2 + 1] = red[0] + h2_bmu[1] + expf(h2_bls[1]) * eps_b2[1];
}

// ---------------------------------------------------------------------------
extern "C" void kernel_launch(void* const* d_in, const int* in_sizes, int n_in,
                              void* d_out, int out_size, void* d_ws, size_t ws_size,
                              hipStream_t stream)
{
    const float* x         = (const float*)d_in[0];
    const float* edge_attr = (const float*)d_in[1];
    const int*   ei        = (const int*)d_in[2];
    const int*   batch     = (const int*)d_in[3];

    const float* We[3]  = { (const float*)d_in[4],  (const float*)d_in[11], (const float*)d_in[18] };
    const float* be[3]  = { (const float*)d_in[5],  (const float*)d_in[12], (const float*)d_in[19] };
    const float* W1[3]  = { (const float*)d_in[6],  (const float*)d_in[13], (const float*)d_in[20] };
    const float* b1[3]  = { (const float*)d_in[7],  (const float*)d_in[14], (const float*)d_in[21] };
    const float* W2[3]  = { (const float*)d_in[8],  (const float*)d_in[15], (const float*)d_in[22] };
    const float* b2[3]  = { (const float*)d_in[9],  (const float*)d_in[16], (const float*)d_in[23] };
    const float* epsl[3]= { (const float*)d_in[10], (const float*)d_in[17], (const float*)d_in[24] };

    const float* h1_wmu = (const float*)d_in[25];
    const float* h1_wls = (const float*)d_in[26];
    const float* h1_bmu = (const float*)d_in[27];
    const float* h1_bls = (const float*)d_in[28];
    const float* h2_wmu = (const float*)d_in[29];
    const float* h2_wls = (const float*)d_in[30];
    const float* h2_bmu = (const float*)d_in[31];
    const float* h2_bls = (const float*)d_in[32];
    const float* eps_w1 = (const float*)d_in[33];
    const float* eps_b1 = (const float*)d_in[34];
    const float* eps_w2 = (const float*)d_in[35];
    const float* eps_b2 = (const float*)d_in[36];

    const int N = in_sizes[0] / 128;
    const int E = in_sizes[1] / 16;
    const int G = out_size / 2;

    float* buf0  = (float*)d_ws;                 // h
    float* buf1  = buf0 + (size_t)N * 256;       // agg
    float* buf2  = buf1 + (size_t)N * 256;       // tmp / hg
    float* w1buf = buf2 + (size_t)N * 256;       // 256*256
    int* rowptr  = (int*)(w1buf + 256 * 256);    // N+1
    int* cursor  = rowptr + (N + 1);             // N
    int* csr_src = cursor + N;                   // E
    int* csr_eid = csr_src + E;                  // E
    // bf16 transposed weights (16B aligned)
    uintptr_t wtp = (uintptr_t)(csr_eid + E);
    wtp = (wtp + 15) & ~(uintptr_t)15;
    unsigned short* wt10 = (unsigned short*)wtp;          // [256][128]
    unsigned short* wt20 = wt10 + 256 * 128;              // [256][256]
    unsigned short* wt11 = wt20 + 256 * 256;
    unsigned short* wt21 = wt11 + 256 * 256;
    unsigned short* wt12 = wt21 + 256 * 256;
    unsigned short* wt22 = wt12 + 256 * 256;
    unsigned short* wt1[3] = { wt10, wt11, wt12 };
    unsigned short* wt2[3] = { wt20, wt21, wt22 };

    const int eblocks     = (E + THREADS - 1) / THREADS;
    const int pool_blocks = (N + 63) / 64;
    const dim3 ggrid((N + 127) / 128, 2);

    float* out = (float*)d_out;

    // ---- build CSR once (edge_index identical for all layers)
    hipMemsetAsync(cursor, 0, (size_t)N * sizeof(int), stream);
    hist_kernel<<<eblocks, THREADS, 0, stream>>>(ei, cursor, E);
    scan_kernel<<<1, 1024, 0, stream>>>(cursor, rowptr, N);
    hipMemsetAsync(cursor, 0, (size_t)N * sizeof(int), stream);
    fill_kernel<<<eblocks, THREADS, 0, stream>>>(ei, rowptr, cursor, csr_src, csr_eid, E);

    // ---- transpose+convert weights (once per call)
    wtrans_kernel<<<dim3(4, 8), THREADS, 0, stream>>>(W1[0], wt1[0], 128);
    wtrans_kernel<<<dim3(8, 8), THREADS, 0, stream>>>(W2[0], wt2[0], 256);
    for (int l = 1; l < 3; l++) {
        wtrans_kernel<<<dim3(8, 8), THREADS, 0, stream>>>(W1[l], wt1[l], 256);
        wtrans_kernel<<<dim3(8, 8), THREADS, 0, stream>>>(W2[l], wt2[l], 256);
    }

    // ---- layer 0 (d = 128, h = x)
    csr_agg_kernel<128><<<(N + 1) / 2, THREADS, 0, stream>>>(
        x, edge_attr, rowptr, csr_src, csr_eid, We[0], be[0], buf1, N);
    mfma_mlp_kernel<128, 0><<<ggrid, THREADS, 0, stream>>>(
        x, buf1, wt1[0], b1[0], epsl[0], buf2, N);
    mfma_mlp_kernel<256, 1><<<ggrid, THREADS, 0, stream>>>(
        buf2, nullptr, wt2[0], b2[0], nullptr, buf0, N);

    // ---- layers 1, 2 (d = 256)
    for (int l = 1; l < 3; l++) {
        csr_agg_kernel<256><<<N, THREADS, 0, stream>>>(
            buf0, edge_attr, rowptr, csr_src, csr_eid, We[l], be[l], buf1, N);
        mfma_mlp_kernel<256, 0><<<ggrid, THREADS, 0, stream>>>(
            buf0, buf1, wt1[l], b1[l], epsl[l], buf2, N);
        mfma_mlp_kernel<256, 1><<<ggrid, THREADS, 0, stream>>>(
            buf2, nullptr, wt2[l], b2[l], nullptr, buf0, N);
    }

    // ---- global add pool -> buf2[0 .. G*256)
    hipMemsetAsync(buf2, 0, (size_t)G * 256 * sizeof(float), stream);
    pool_kernel<<<pool_blocks, THREADS, 0, stream>>>(buf0, batch, buf2, N);

    // ---- Bayesian head
    wprep_kernel<<<(256 * 256 + THREADS - 1) / THREADS, THREADS, 0, stream>>>(
        h1_wmu, h1_wls, eps_w1, w1buf, 256 * 256);
    head_kernel<<<G, THREADS, 0, stream>>>(
        buf2, w1buf, h1_bmu, h1_bls, eps_b1,
        h2_wmu, h2_wls, eps_w2, h2_bmu, h2_bls, eps_b2, out);
}

// Round 4
// 940.993 us; speedup vs baseline: 2.1698x; 1.0272x over previous
//
#include <hip/hip_runtime.h>
#include <hip/hip_bf16.h>
#include <math.h>

// ---------------------------------------------------------------------------
// GINE x3 + global_add_pool + Bayesian head.
// Round 4: all intermediates bf16 (L3-resident working set), edge_attr
// pre-sorted into CSR order, bf16 MFMA GEMMs with bf16 in/out.
// ---------------------------------------------------------------------------

#define THREADS 256

typedef __attribute__((ext_vector_type(8))) short bf16x8;
typedef __attribute__((ext_vector_type(4))) float f32x4;

__device__ __forceinline__ unsigned short f2bf(float x) {
    __hip_bfloat16 h = __float2bfloat16(x);
    return __builtin_bit_cast(unsigned short, h);
}
__device__ __forceinline__ float bflo(unsigned u) {
    return __builtin_bit_cast(float, u << 16);
}
__device__ __forceinline__ float bfhi(unsigned u) {
    return __builtin_bit_cast(float, u & 0xffff0000u);
}
__device__ __forceinline__ unsigned pk(float a, float b) {
    return (unsigned)f2bf(a) | ((unsigned)f2bf(b) << 16);
}

// ---------------- CSR build: histogram of dst
__global__ __launch_bounds__(THREADS) void hist_kernel(
    const int* __restrict__ ei, int* __restrict__ deg, int E)
{
    int e = blockIdx.x * THREADS + threadIdx.x;
    if (e < E) atomicAdd(&deg[ei[E + e]], 1);
}

// ---------------- CSR build: single-block exclusive scan -> rowptr[0..n]
__global__ __launch_bounds__(1024) void scan_kernel(
    const int* __restrict__ deg, int* __restrict__ rowptr, int n)
{
    __shared__ int s[1024];
    __shared__ int carry_s;
    const int t = threadIdx.x;
    if (t == 0) carry_s = 0;
    __syncthreads();
    for (int base = 0; base < n; base += 1024) {
        int i = base + t;
        s[t] = (i < n) ? deg[i] : 0;
        __syncthreads();
        for (int off = 1; off < 1024; off <<= 1) {
            int add = (t >= off) ? s[t - off] : 0;
            __syncthreads();
            s[t] += add;
            __syncthreads();
        }
        int incl = s[t];
        int carry = carry_s;
        if (i < n) rowptr[i + 1] = carry + incl;
        __syncthreads();
        if (t == 1023) carry_s = carry + incl;
        __syncthreads();
    }
    if (t == 0) rowptr[0] = 0;
}

// ---------------- CSR build: scatter edge ids into slots
__global__ __launch_bounds__(THREADS) void fill_kernel(
    const int* __restrict__ ei, const int* __restrict__ rowptr,
    int* __restrict__ cursor, int* __restrict__ csr_src,
    int* __restrict__ csr_eid, int E)
{
    int e = blockIdx.x * THREADS + threadIdx.x;
    if (e >= E) return;
    int s = ei[e], d = ei[E + e];
    int pos  = atomicAdd(&cursor[d], 1);
    int slot = rowptr[d] + pos;
    csr_src[slot] = s;
    csr_eid[slot] = e;
}

// ---------------- sort edge_attr into CSR slot order (streaming reads later)
__global__ __launch_bounds__(THREADS) void easort_kernel(
    const float* __restrict__ edge_attr, const int* __restrict__ csr_eid,
    float* __restrict__ ea_sorted, int E)
{
    int s = blockIdx.x * THREADS + threadIdx.x;
    if (s >= E) return;
    int eid = csr_eid[s];
    const float4* a = (const float4*)(edge_attr + (size_t)eid * 16);
    float4* d = (float4*)(ea_sorted + (size_t)s * 16);
    d[0] = a[0]; d[1] = a[1]; d[2] = a[2]; d[3] = a[3];
}

// ---------------- x -> bf16 copy
__global__ __launch_bounds__(THREADS) void xprep_kernel(
    const float* __restrict__ x, unsigned short* __restrict__ xbf, int n4)
{
    int i = blockIdx.x * THREADS + threadIdx.x;
    if (i >= n4) return;
    float4 v = ((const float4*)x)[i];
    uint2 p;
    p.x = pk(v.x, v.y);
    p.y = pk(v.z, v.w);
    ((uint2*)xbf)[i] = p;
}

// ---------------- aggregation: aggbf[n][k] = sum_{e: dst=n} relu(h[src][k]+proj)
// 2 features per lane; D=128 -> 1 wave/node (4 nodes/block), D=256 -> 2 waves.
template<int D>
__global__ __launch_bounds__(THREADS) void csr_agg_kernel(
    const unsigned short* __restrict__ hbf,   // [N, D] bf16
    const float* __restrict__ ea_sorted,      // [E, 16] f32, CSR order
    const int*   __restrict__ rowptr,
    const int*   __restrict__ csr_src,
    const float* __restrict__ We,             // [16, D]
    const float* __restrict__ be,             // [D]
    unsigned short* __restrict__ aggbf,       // [N, D] bf16
    int nnodes)
{
    constexpr int LPN = D / 2;
    constexpr int NPB = THREADS / LPN;
    const int t   = threadIdx.x;
    const int tid = t & (LPN - 1);
    const int sub = t / LPN;
    const int n   = blockIdx.x * NPB + sub;
    if (n >= nnodes) return;
    const int k0 = tid * 2;

    float w0[16], w1[16];
#pragma unroll
    for (int i = 0; i < 16; i++) {
        w0[i] = We[i * D + k0];
        w1[i] = We[i * D + k0 + 1];
    }
    const float b0 = be[k0], b1 = be[k0 + 1];

    float acc0 = 0.f, acc1 = 0.f;
    const int beg = rowptr[n], end = rowptr[n + 1];
    for (int s = beg; s < end; ++s) {
        int src = csr_src[s];
        unsigned hv = *(const unsigned*)(hbf + (size_t)src * D + k0);
        const float4* ea = (const float4*)(ea_sorted + (size_t)s * 16);
        float4 a0 = ea[0], a1 = ea[1], a2 = ea[2], a3 = ea[3];
        float e0 = b0, e1 = b1;
        e0 += w0[0]*a0.x + w0[1]*a0.y + w0[2]*a0.z + w0[3]*a0.w;
        e0 += w0[4]*a1.x + w0[5]*a1.y + w0[6]*a1.z + w0[7]*a1.w;
        e0 += w0[8]*a2.x + w0[9]*a2.y + w0[10]*a2.z + w0[11]*a2.w;
        e0 += w0[12]*a3.x + w0[13]*a3.y + w0[14]*a3.z + w0[15]*a3.w;
        e1 += w1[0]*a0.x + w1[1]*a0.y + w1[2]*a0.z + w1[3]*a0.w;
        e1 += w1[4]*a1.x + w1[5]*a1.y + w1[6]*a1.z + w1[7]*a1.w;
        e1 += w1[8]*a2.x + w1[9]*a2.y + w1[10]*a2.z + w1[11]*a2.w;
        e1 += w1[12]*a3.x + w1[13]*a3.y + w1[14]*a3.z + w1[15]*a3.w;
        acc0 += fmaxf(bflo(hv) + e0, 0.f);
        acc1 += fmaxf(bfhi(hv) + e1, 0.f);
    }
    *(unsigned*)(aggbf + (size_t)n * D + k0) = pk(acc0, acc1);
}

// ---------------- W transpose + bf16 convert: W[K,256] f32 -> Wt[256,K] bf16
__global__ __launch_bounds__(THREADS) void wtrans_kernel(
    const float* __restrict__ W, unsigned short* __restrict__ Wt, int K)
{
    __shared__ float tile[32][33];
    const int kb = blockIdx.x * 32, nb = blockIdx.y * 32;
    const int tx = threadIdx.x & 31, ty = threadIdx.x >> 5;
#pragma unroll
    for (int i = ty; i < 32; i += 8)
        tile[i][tx] = W[(size_t)(kb + i) * 256 + nb + tx];
    __syncthreads();
#pragma unroll
    for (int i = ty; i < 32; i += 8)
        Wt[(size_t)(nb + i) * K + kb + tx] = f2bf(tile[tx][i]);
}

// ---------------- MFMA node-MLP GEMM (bf16 in, bf16 out):
// out[r][n] = relu( A[r][:] @ Wt[n][:] + bias[n] )
// MODE 0: A = (1+eps)*hin + agg    MODE 1: A = hin
template<int K, int MODE>
__global__ __launch_bounds__(THREADS) void mfma_mlp_kernel(
    const unsigned short* __restrict__ hin,   // [nrows, K] bf16
    const unsigned short* __restrict__ agg,   // [nrows, K] bf16 (MODE 0)
    const unsigned short* __restrict__ Wt,    // [256, K] bf16
    const float* __restrict__ bias,           // [256]
    const float* __restrict__ epsp,           // [1] (MODE 0)
    unsigned short* __restrict__ out,         // [nrows, 256] bf16
    int nrows)
{
    constexpr int BM = 128, BK = 64;
    constexpr int LDR = BK + 8;               // 72 shorts = 144 B row stride
    __shared__ short As[BM * LDR];
    __shared__ short Bs[128 * LDR];

    const int t    = threadIdx.x;
    const int lane = t & 63;
    const int wid  = t >> 6;
    const int wm   = wid >> 1, wn = wid & 1;
    const int l15  = lane & 15, lgr = lane >> 4;

    const int r0 = blockIdx.x * BM;
    const int n0 = blockIdx.y * 128;

    float scale = 1.0f;
    if (MODE == 0) scale = 1.0f + epsp[0];

    f32x4 acc[4][4];
#pragma unroll
    for (int a = 0; a < 4; a++)
#pragma unroll
        for (int b = 0; b < 4; b++) acc[a][b] = (f32x4){0.f, 0.f, 0.f, 0.f};

    for (int k0 = 0; k0 < K; k0 += BK) {
        // ---- stage A: 128 rows x 64 k bf16 (4 x 16B chunks per thread)
#pragma unroll
        for (int c = 0; c < 4; c++) {
            int idx = t + c * THREADS;        // 0..1023
            int r   = idx >> 3;               // 0..127
            int kq  = idx & 7;                // 16B chunk within row
            int row = r0 + r;
            uint4 o = make_uint4(0, 0, 0, 0);
            if (row < nrows) {
                size_t g = (size_t)row * K + k0 + kq * 8;
                uint4 hv = *(const uint4*)(hin + g);
                if (MODE == 0) {
                    uint4 av = *(const uint4*)(agg + g);
                    o.x = pk(scale * bflo(hv.x) + bflo(av.x),
                             scale * bfhi(hv.x) + bfhi(av.x));
                    o.y = pk(scale * bflo(hv.y) + bflo(av.y),
                             scale * bfhi(hv.y) + bfhi(av.y));
                    o.z = pk(scale * bflo(hv.z) + bflo(av.z),
                             scale * bfhi(hv.z) + bfhi(av.z));
                    o.w = pk(scale * bflo(hv.w) + bflo(av.w),
                             scale * bfhi(hv.w) + bfhi(av.w));
                } else {
                    o = hv;
                }
            }
            *(uint4*)(&As[r * LDR + kq * 8]) = o;
        }
        // ---- stage B: 128 n-rows x 64 k bf16 (4 x 16B per thread)
#pragma unroll
        for (int c = 0; c < 4; c++) {
            int idx = t + c * THREADS;        // 0..1023
            int n   = idx >> 3;               // 0..127
            int kq  = idx & 7;
            uint4 w = *(const uint4*)(Wt + (size_t)(n0 + n) * K + k0 + kq * 8);
            *(uint4*)(&Bs[n * LDR + kq * 8]) = w;
        }
        __syncthreads();

        // ---- compute: 2 k-slices of 32, 4x4 fragments per wave
#pragma unroll
        for (int ks = 0; ks < 2; ks++) {
            bf16x8 af[4], bfr[4];
#pragma unroll
            for (int mf = 0; mf < 4; mf++)
                af[mf] = *(const bf16x8*)(&As[(wm * 64 + mf * 16 + l15) * LDR + ks * 32 + lgr * 8]);
#pragma unroll
            for (int nf = 0; nf < 4; nf++)
                bfr[nf] = *(const bf16x8*)(&Bs[(wn * 64 + nf * 16 + l15) * LDR + ks * 32 + lgr * 8]);
#pragma unroll
            for (int mf = 0; mf < 4; mf++)
#pragma unroll
                for (int nf = 0; nf < 4; nf++)
                    acc[mf][nf] = __builtin_amdgcn_mfma_f32_16x16x32_bf16(
                        af[mf], bfr[nf], acc[mf][nf], 0, 0, 0);
        }
        __syncthreads();
    }

    // ---- epilogue: bias + relu, bf16 store
#pragma unroll
    for (int nf = 0; nf < 4; nf++) {
        int col = n0 + wn * 64 + nf * 16 + l15;
        float bcol = bias[col];
#pragma unroll
        for (int mf = 0; mf < 4; mf++) {
            f32x4 v = acc[mf][nf];
#pragma unroll
            for (int r = 0; r < 4; r++) {
                int row = r0 + wm * 64 + mf * 16 + lgr * 4 + r;
                if (row < nrows)
                    out[(size_t)row * 256 + col] = f2bf(fmaxf(v[r] + bcol, 0.f));
            }
        }
    }
}

// ---------------- global add pool (batch sorted: run-length compress atomics)
__global__ __launch_bounds__(THREADS) void pool_kernel(
    const unsigned short* __restrict__ hbf,  // [N, 256] bf16
    const int*   __restrict__ batch,         // [N]
    float*       __restrict__ hg,            // [G, 256] f32
    int nnodes)
{
    constexpr int CH = 64;
    __shared__ int b_s[CH];
    const int t  = threadIdx.x;
    const int v0 = blockIdx.x * CH;
    int cnt = nnodes - v0;
    if (cnt > CH) cnt = CH;
    if (cnt <= 0) return;
    if (t < cnt) b_s[t] = batch[v0 + t];
    __syncthreads();

    int curb  = b_s[0];
    float acc = 0.f;
    for (int v = 0; v < cnt; v++) {
        int b = b_s[v];
        if (b != curb) {
            atomicAdd(&hg[(size_t)curb * 256 + t], acc);
            acc = 0.f; curb = b;
        }
        unsigned short u = hbf[(size_t)(v0 + v) * 256 + t];
        acc += __builtin_bit_cast(float, (unsigned)u << 16);
    }
    atomicAdd(&hg[(size_t)curb * 256 + t], acc);
}

// ---------------- Bayesian weight materialization: w = mu + exp(ls)*eps
__global__ void wprep_kernel(const float* __restrict__ mu,
                             const float* __restrict__ ls,
                             const float* __restrict__ eps,
                             float* __restrict__ w, int n)
{
    int i = blockIdx.x * THREADS + threadIdx.x;
    if (i < n) w[i] = mu[i] + expf(ls[i]) * eps[i];
}

// ---------------- head: out[g] = silu(hg @ w1 + b1) @ w2 + b2
__global__ __launch_bounds__(THREADS) void head_kernel(
    const float* __restrict__ hg,     // [G, 256]
    const float* __restrict__ w1,     // [256, 256] materialized
    const float* __restrict__ h1_bmu, const float* __restrict__ h1_bls,
    const float* __restrict__ eps_b1,
    const float* __restrict__ h2_wmu, const float* __restrict__ h2_wls,
    const float* __restrict__ eps_w2,
    const float* __restrict__ h2_bmu, const float* __restrict__ h2_bls,
    const float* __restrict__ eps_b2,
    float* __restrict__ out)          // [G, 2]
{
    __shared__ float x_s[256];
    __shared__ float red[256];
    const int t = threadIdx.x;
    const int g = blockIdx.x;

    x_s[t] = hg[(size_t)g * 256 + t];
    __syncthreads();

    float acc = h1_bmu[t] + expf(h1_bls[t]) * eps_b1[t];
    for (int kk = 0; kk < 256; kk++) acc += x_s[kk] * w1[kk * 256 + t];
    float h1v = acc / (1.f + expf(-acc));   // silu

    float w2a = h2_wmu[t * 2 + 0] + expf(h2_wls[t * 2 + 0]) * eps_w2[t * 2 + 0];
    float w2b = h2_wmu[t * 2 + 1] + expf(h2_wls[t * 2 + 1]) * eps_w2[t * 2 + 1];

    red[t] = h1v * w2a;
    __syncthreads();
    for (int s = 128; s > 0; s >>= 1) {
        if (t < s) red[t] += red[t + s];
        __syncthreads();
    }
    if (t == 0) out[(size_t)g * 2 + 0] = red[0] + h2_bmu[0] + expf(h2_bls[0]) * eps_b2[0];
    __syncthreads();

    red[t] = h1v * w2b;
    __syncthreads();
    for (int s = 128; s > 0; s >>= 1) {
        if (t < s) red[t] += red[t + s];
        __syncthreads();
    }
    if (t == 0) out[(size_t)g * 2 + 1] = red[0] + h2_bmu[1] + expf(h2_bls[1]) * eps_b2[1];
}

// ---------------------------------------------------------------------------
extern "C" void kernel_launch(void* const* d_in, const int* in_sizes, int n_in,
                              void* d_out, int out_size, void* d_ws, size_t ws_size,
                              hipStream_t stream)
{
    const float* x         = (const float*)d_in[0];
    const float* edge_attr = (const float*)d_in[1];
    const int*   ei        = (const int*)d_in[2];
    const int*   batch     = (const int*)d_in[3];

    const float* We[3]  = { (const float*)d_in[4],  (const float*)d_in[11], (const float*)d_in[18] };
    const float* be[3]  = { (const float*)d_in[5],  (const float*)d_in[12], (const float*)d_in[19] };
    const float* W1[3]  = { (const float*)d_in[6],  (const float*)d_in[13], (const float*)d_in[20] };
    const float* b1[3]  = { (const float*)d_in[7],  (const float*)d_in[14], (const float*)d_in[21] };
    const float* W2[3]  = { (const float*)d_in[8],  (const float*)d_in[15], (const float*)d_in[22] };
    const float* b2[3]  = { (const float*)d_in[9],  (const float*)d_in[16], (const float*)d_in[23] };
    const float* epsl[3]= { (const float*)d_in[10], (const float*)d_in[17], (const float*)d_in[24] };

    const float* h1_wmu = (const float*)d_in[25];
    const float* h1_wls = (const float*)d_in[26];
    const float* h1_bmu = (const float*)d_in[27];
    const float* h1_bls = (const float*)d_in[28];
    const float* h2_wmu = (const float*)d_in[29];
    const float* h2_wls = (const float*)d_in[30];
    const float* h2_bmu = (const float*)d_in[31];
    const float* h2_bls = (const float*)d_in[32];
    const float* eps_w1 = (const float*)d_in[33];
    const float* eps_b1 = (const float*)d_in[34];
    const float* eps_w2 = (const float*)d_in[35];
    const float* eps_b2 = (const float*)d_in[36];

    const int N = in_sizes[0] / 128;
    const int E = in_sizes[1] / 16;
    const int G = out_size / 2;

    // ---- carve workspace (256B aligned chunks)
    uintptr_t p = (uintptr_t)d_ws;
    auto carve = [&](size_t bytes) -> void* {
        void* r = (void*)p;
        p = (p + bytes + 255) & ~(uintptr_t)255;
        return r;
    };
    float* hg        = (float*)carve((size_t)G * 256 * 4);
    float* w1buf     = (float*)carve(256 * 256 * 4);
    float* ea_sorted = (float*)carve((size_t)E * 16 * 4);
    int*   rowptr    = (int*)carve((size_t)(N + 1) * 4);
    int*   cursor    = (int*)carve((size_t)N * 4);
    int*   csr_src   = (int*)carve((size_t)E * 4);
    int*   csr_eid   = (int*)carve((size_t)E * 4);
    unsigned short* hbf   = (unsigned short*)carve((size_t)N * 256 * 2);
    unsigned short* aggbf = (unsigned short*)carve((size_t)N * 256 * 2);
    unsigned short* tmpbf = (unsigned short*)carve((size_t)N * 256 * 2);
    unsigned short* xbf   = (unsigned short*)carve((size_t)N * 128 * 2);
    unsigned short* wt1[3], *wt2[3];
    wt1[0] = (unsigned short*)carve(256 * 128 * 2);
    for (int l = 0; l < 3; l++) {
        if (l) wt1[l] = (unsigned short*)carve(256 * 256 * 2);
        wt2[l] = (unsigned short*)carve(256 * 256 * 2);
    }

    const int eblocks     = (E + THREADS - 1) / THREADS;
    const int pool_blocks = (N + 63) / 64;
    const dim3 ggrid((N + 127) / 128, 2);

    float* out = (float*)d_out;

    // ---- build CSR once (edge_index identical for all layers)
    hipMemsetAsync(cursor, 0, (size_t)N * sizeof(int), stream);
    hist_kernel<<<eblocks, THREADS, 0, stream>>>(ei, cursor, E);
    scan_kernel<<<1, 1024, 0, stream>>>(cursor, rowptr, N);
    hipMemsetAsync(cursor, 0, (size_t)N * sizeof(int), stream);
    fill_kernel<<<eblocks, THREADS, 0, stream>>>(ei, rowptr, cursor, csr_src, csr_eid, E);
    easort_kernel<<<eblocks, THREADS, 0, stream>>>(edge_attr, csr_eid, ea_sorted, E);
    xprep_kernel<<<(N * 32 + THREADS - 1) / THREADS, THREADS, 0, stream>>>(x, xbf, N * 32);

    // ---- transpose+convert weights (once per call)
    wtrans_kernel<<<dim3(4, 8), THREADS, 0, stream>>>(W1[0], wt1[0], 128);
    wtrans_kernel<<<dim3(8, 8), THREADS, 0, stream>>>(W2[0], wt2[0], 256);
    for (int l = 1; l < 3; l++) {
        wtrans_kernel<<<dim3(8, 8), THREADS, 0, stream>>>(W1[l], wt1[l], 256);
        wtrans_kernel<<<dim3(8, 8), THREADS, 0, stream>>>(W2[l], wt2[l], 256);
    }

    // ---- layer 0 (d = 128, h = xbf)
    csr_agg_kernel<128><<<(N + 3) / 4, THREADS, 0, stream>>>(
        xbf, ea_sorted, rowptr, csr_src, We[0], be[0], aggbf, N);
    mfma_mlp_kernel<128, 0><<<ggrid, THREADS, 0, stream>>>(
        xbf, aggbf, wt1[0], b1[0], epsl[0], tmpbf, N);
    mfma_mlp_kernel<256, 1><<<ggrid, THREADS, 0, stream>>>(
        tmpbf, nullptr, wt2[0], b2[0], nullptr, hbf, N);

    // ---- layers 1, 2 (d = 256)
    for (int l = 1; l < 3; l++) {
        csr_agg_kernel<256><<<(N + 1) / 2, THREADS, 0, stream>>>(
            hbf, ea_sorted, rowptr, csr_src, We[l], be[l], aggbf, N);
        mfma_mlp_kernel<256, 0><<<ggrid, THREADS, 0, stream>>>(
            hbf, aggbf, wt1[l], b1[l], epsl[l], tmpbf, N);
        mfma_mlp_kernel<256, 1><<<ggrid, THREADS, 0, stream>>>(
            tmpbf, nullptr, wt2[l], b2[l], nullptr, hbf, N);
    }

    // ---- global add pool -> hg
    hipMemsetAsync(hg, 0, (size_t)G * 256 * sizeof(float), stream);
    pool_kernel<<<pool_blocks, THREADS, 0, stream>>>(hbf, batch, hg, N);

    // ---- Bayesian head
    wprep_kernel<<<(256 * 256 + THREADS - 1) / THREADS, THREADS, 0, stream>>>(
        h1_wmu, h1_wls, eps_w1, w1buf, 256 * 256);
    head_kernel<<<G, THREADS, 0, stream>>>(
        hg, w1buf, h1_bmu, h1_bls, eps_b1,
        h2_wmu, h2_wls, eps_w2, h2_bmu, h2_bls, eps_b2, out);
}